// Round 2
// baseline (509.060 us; speedup 1.0000x reference)
//
#include <hip/hip_runtime.h>
#include <math.h>

namespace {
constexpr int B = 8, L = 200, H = 128, NH = 4;
constexpr int LP = 224;                            // L padded to multiple of 32
constexpr float NEG = -4294967295.0f;              // -(2^32)+1
constexpr float QSCALE = 0.17677669529663687f;     // 1/sqrt(32)
}

// ---------------------------------------------------------------------------
// Kernel 1: Q/K/V projections (nn.Linear: y = x @ W.T + b), fused with
//   Q *= 1/sqrt(HD);  K += abs_pos_K;  V += abs_pos_V.
// grid = 3 * (B*L/8) blocks, 256 threads; each block does 8 rows of one proj.
// ---------------------------------------------------------------------------
extern "C" __global__ __launch_bounds__(256) void tama_proj(
    const float* __restrict__ queries, const float* __restrict__ keys,
    const float* __restrict__ apK, const float* __restrict__ apV,
    const float* __restrict__ Wq, const float* __restrict__ bq,
    const float* __restrict__ Wk, const float* __restrict__ bk,
    const float* __restrict__ Wv, const float* __restrict__ bv,
    float* __restrict__ Qs, float* __restrict__ KpK, float* __restrict__ VpV)
{
    const int nrb = (B * L) / 8;            // 200 row-blocks per projection
    const int which = blockIdx.x / nrb;     // 0:Q 1:K 2:V
    const int r0 = (blockIdx.x % nrb) * 8;
    const int t = threadIdx.x;

    const float* __restrict__ x    = (which == 0) ? queries : keys;
    const float* __restrict__ W    = (which == 0) ? Wq : (which == 1) ? Wk : Wv;
    const float* __restrict__ bias = (which == 0) ? bq : (which == 1) ? bk : bv;

    __shared__ float xs[8][H];
    *(float4*)(&xs[0][0] + t * 4) = *(const float4*)(x + (size_t)r0 * H + t * 4);
    __syncthreads();

    const int d  = t & (H - 1);
    const int rh = (t >> 7) * 4;            // local row base: 0 or 4
    float a0 = 0.f, a1 = 0.f, a2 = 0.f, a3 = 0.f;
    const float4* __restrict__ wrow4 = (const float4*)(W + (size_t)d * H);
    #pragma unroll 8
    for (int j4 = 0; j4 < H / 4; ++j4) {
        const float4 w = wrow4[j4];
        const int j = j4 * 4;
        a0 += xs[rh + 0][j] * w.x + xs[rh + 0][j + 1] * w.y
            + xs[rh + 0][j + 2] * w.z + xs[rh + 0][j + 3] * w.w;
        a1 += xs[rh + 1][j] * w.x + xs[rh + 1][j + 1] * w.y
            + xs[rh + 1][j + 2] * w.z + xs[rh + 1][j + 3] * w.w;
        a2 += xs[rh + 2][j] * w.x + xs[rh + 2][j + 1] * w.y
            + xs[rh + 2][j + 2] * w.z + xs[rh + 2][j + 3] * w.w;
        a3 += xs[rh + 3][j] * w.x + xs[rh + 3][j + 1] * w.y
            + xs[rh + 3][j + 2] * w.z + xs[rh + 3][j + 3] * w.w;
    }
    const float bb = bias[d];
    float o[4] = {a0 + bb, a1 + bb, a2 + bb, a3 + bb};

    if (which == 0) {
        #pragma unroll
        for (int rr = 0; rr < 4; ++rr)
            Qs[(size_t)(r0 + rh + rr) * H + d] = o[rr] * QSCALE;
    } else if (which == 1) {
        #pragma unroll
        for (int rr = 0; rr < 4; ++rr) {
            const size_t idx = (size_t)(r0 + rh + rr) * H + d;
            KpK[idx] = o[rr] + apK[idx];
        }
    } else {
        #pragma unroll
        for (int rr = 0; rr < 4; ++rr) {
            const size_t idx = (size_t)(r0 + rh + rr) * H + d;
            VpV[idx] = o[rr] + apV[idx];
        }
    }
}

// ---------------------------------------------------------------------------
// Kernel 2: fused attention. One block per (b,q). 256 threads:
//   thread t -> column c4=(t&31)*4 (float4), k-row krow=t>>5, head h=(t&31)>>3.
// Streaming loops unrolled x4 (32 rows / iter, 12 float4 loads in flight per
// thread) to hide HBM latency. Tail rows: global row index clamped to L-1
// (harmless reads), score writes guarded by k<=q, probs zero-padded to LP.
// ---------------------------------------------------------------------------
extern "C" __global__ __launch_bounds__(256) void tama_attn(
    const float* __restrict__ Qs, const float* __restrict__ KpK,
    const float* __restrict__ VpV, const int* __restrict__ time_mask,
    const float* __restrict__ tK, const float* __restrict__ tV,
    const float* __restrict__ dK, const float* __restrict__ dV,
    float* __restrict__ out)
{
    const int bq = (int)gridDim.x - 1 - (int)blockIdx.x;  // heavy (high-q) first
    const int b = bq / L, q = bq - b * L;
    const int t = threadIdx.x;

    __shared__ float p[NH][LP];     // probs per head, zero-padded to LP
    __shared__ float red[8][H];     // output reduction scratch

    const int c4   = (t & 31) * 4;
    const int krow = t >> 5;        // 0..7
    const int h    = (t & 31) >> 3; // head 0..3
    const int sg   = t & 7;

    const bool tmq = time_mask[b * L + q] != 0;  // row-mask: whole q row NEG
    const int kA = tmq ? 0 : (q + 1);            // score phase extent
    const int kB = tmq ? L : (q + 1);            // output phase extent

    const float4 q4 = *(const float4*)(Qs + (size_t)bq * H + c4);
    const float* __restrict__ tKb = tK + (size_t)bq * L * H;
    const float* __restrict__ dKb = dK + (size_t)bq * L * H;
    const float* __restrict__ kpb = KpK + (size_t)b * L * H;

    // ---- Phase A: scores, 32 rows / iteration ----
    for (int k0 = 0; k0 < kA; k0 += 32) {
        float4 a[4], c[4], e[4];
        int ku[4];
        #pragma unroll
        for (int u = 0; u < 4; ++u) {
            ku[u] = k0 + krow + 8 * u;
            const int kc = ku[u] < L ? ku[u] : L - 1;  // clamp: harmless read
            a[u] = *(const float4*)(tKb + (size_t)kc * H + c4);
            c[u] = *(const float4*)(dKb + (size_t)kc * H + c4);
            e[u] = *(const float4*)(kpb + (size_t)kc * H + c4);
        }
        #pragma unroll
        for (int u = 0; u < 4; ++u) {
            float s = q4.x * (a[u].x + c[u].x + e[u].x)
                    + q4.y * (a[u].y + c[u].y + e[u].y)
                    + q4.z * (a[u].z + c[u].z + e[u].z)
                    + q4.w * (a[u].w + c[u].w + e[u].w);
            s += __shfl_xor(s, 1);
            s += __shfl_xor(s, 2);
            s += __shfl_xor(s, 4);
            if (sg == 0 && ku[u] <= q) p[h][ku[u]] = s;
        }
    }
    __syncthreads();

    // ---- Softmax: wave w handles head w; lanes cover k = lane + 64*i ----
    {
        const int wv = t >> 6;
        const int lane = t & 63;
        float s0 = p[wv][lane];
        float s1 = p[wv][lane + 64];
        float s2 = p[wv][lane + 128];
        float s3 = (lane < L - 192) ? p[wv][lane + 192] : NEG;
        if (tmq || lane > q)       s0 = NEG;
        if (tmq || lane + 64 > q)  s1 = NEG;
        if (tmq || lane + 128 > q) s2 = NEG;
        if (tmq || lane + 192 > q) s3 = NEG;   // always true for lane >= 8
        float m = fmaxf(fmaxf(s0, s1), fmaxf(s2, s3));
        #pragma unroll
        for (int off = 32; off; off >>= 1) m = fmaxf(m, __shfl_xor(m, off));
        const float e0 = __expf(s0 - m);       // exp(NEG-m) underflows to 0.0f
        const float e1 = __expf(s1 - m);
        const float e2 = __expf(s2 - m);
        const float e3 = (lane < L - 192) ? __expf(s3 - m) : 0.f;
        float sum = e0 + e1 + e2 + e3;
        #pragma unroll
        for (int off = 32; off; off >>= 1) sum += __shfl_xor(sum, off);
        const float inv = 1.0f / sum;
        p[wv][lane]       = e0 * inv;
        p[wv][lane + 64]  = e1 * inv;
        p[wv][lane + 128] = e2 * inv;
        if (lane < L - 192) p[wv][lane + 192] = e3 * inv;
        if (lane < LP - L) p[wv][L + lane] = 0.f;   // zero pad 200..223
    }
    __syncthreads();

    // ---- Phase B: out[c] = sum_k p[h][k] * (VpV + tV + dV)[k][c] ----
    const float* __restrict__ tVb = tV + (size_t)bq * L * H;
    const float* __restrict__ dVb = dV + (size_t)bq * L * H;
    const float* __restrict__ vpb = VpV + (size_t)b * L * H;
    float ax = 0.f, ay = 0.f, az = 0.f, aw = 0.f;
    for (int k0 = 0; k0 < kB; k0 += 32) {
        float4 a[4], c[4], e[4];
        float pk[4];
        #pragma unroll
        for (int u = 0; u < 4; ++u) {
            const int ku = k0 + krow + 8 * u;          // <= 223 < LP
            const int kc = ku < L ? ku : L - 1;        // clamp: harmless read
            pk[u] = p[h][ku];                          // 0 beyond kB (exact)
            a[u] = *(const float4*)(tVb + (size_t)kc * H + c4);
            c[u] = *(const float4*)(dVb + (size_t)kc * H + c4);
            e[u] = *(const float4*)(vpb + (size_t)kc * H + c4);
        }
        #pragma unroll
        for (int u = 0; u < 4; ++u) {
            ax += pk[u] * (a[u].x + c[u].x + e[u].x);
            ay += pk[u] * (a[u].y + c[u].y + e[u].y);
            az += pk[u] * (a[u].z + c[u].z + e[u].z);
            aw += pk[u] * (a[u].w + c[u].w + e[u].w);
        }
    }
    red[krow][c4 + 0] = ax;
    red[krow][c4 + 1] = ay;
    red[krow][c4 + 2] = az;
    red[krow][c4 + 3] = aw;
    __syncthreads();
    if (t < 32) {
        float4 r = {0.f, 0.f, 0.f, 0.f};
        #pragma unroll
        for (int j = 0; j < 8; ++j) {
            r.x += red[j][t * 4 + 0];
            r.y += red[j][t * 4 + 1];
            r.z += red[j][t * 4 + 2];
            r.w += red[j][t * 4 + 3];
        }
        *(float4*)(out + (size_t)bq * H + t * 4) = r;
    }
}

// ---------------------------------------------------------------------------
extern "C" void kernel_launch(void* const* d_in, const int* in_sizes, int n_in,
                              void* d_out, int out_size, void* d_ws, size_t ws_size,
                              hipStream_t stream)
{
    const float* queries   = (const float*)d_in[0];
    const float* keys      = (const float*)d_in[1];
    const int*   time_mask = (const int*)d_in[2];
    // d_in[3] attn_mask unused: it is exactly triu(ones, k=1), i.e. (k > q)
    const float* tK  = (const float*)d_in[4];
    const float* tV  = (const float*)d_in[5];
    const float* dK  = (const float*)d_in[6];
    const float* dV  = (const float*)d_in[7];
    const float* apK = (const float*)d_in[8];
    const float* apV = (const float*)d_in[9];
    const float* Wq  = (const float*)d_in[10];
    const float* bqv = (const float*)d_in[11];
    const float* Wk  = (const float*)d_in[12];
    const float* bkv = (const float*)d_in[13];
    const float* Wv  = (const float*)d_in[14];
    const float* bvv = (const float*)d_in[15];

    float* Qs  = (float*)d_ws;                 // [B*L*H]
    float* KpK = Qs + (size_t)B * L * H;       // [B*L*H]
    float* VpV = KpK + (size_t)B * L * H;      // [B*L*H]  (total 2.46 MB)
    float* outp = (float*)d_out;

    hipLaunchKernelGGL(tama_proj, dim3(3 * (B * L) / 8), dim3(256), 0, stream,
                       queries, keys, apK, apV, Wq, bqv, Wk, bkv, Wv, bvv,
                       Qs, KpK, VpV);
    hipLaunchKernelGGL(tama_attn, dim3(B * L), dim3(256), 0, stream,
                       Qs, KpK, VpV, time_mask, tK, tV, dK, dV, outp);
}

// Round 3
// 506.352 us; speedup vs baseline: 1.0053x; 1.0053x over previous
//
#include <hip/hip_runtime.h>
#include <math.h>

namespace {
constexpr int B = 8, L = 200, H = 128, NH = 4;
constexpr int LP = 224;                            // L padded to multiple of 32
constexpr float NEG = -4294967295.0f;              // -(2^32)+1
constexpr float QSCALE = 0.17677669529663687f;     // 1/sqrt(32)
}

// ---------------------------------------------------------------------------
// Kernel 1: Q/K/V projections (nn.Linear: y = x @ W.T + b), fused with
//   Q *= 1/sqrt(HD);  K += abs_pos_K;  V += abs_pos_V.
// ---------------------------------------------------------------------------
extern "C" __global__ __launch_bounds__(256) void tama_proj(
    const float* __restrict__ queries, const float* __restrict__ keys,
    const float* __restrict__ apK, const float* __restrict__ apV,
    const float* __restrict__ Wq, const float* __restrict__ bq,
    const float* __restrict__ Wk, const float* __restrict__ bk,
    const float* __restrict__ Wv, const float* __restrict__ bv,
    float* __restrict__ Qs, float* __restrict__ KpK, float* __restrict__ VpV)
{
    const int nrb = (B * L) / 8;            // 200 row-blocks per projection
    const int which = blockIdx.x / nrb;     // 0:Q 1:K 2:V
    const int r0 = (blockIdx.x % nrb) * 8;
    const int t = threadIdx.x;

    const float* __restrict__ x    = (which == 0) ? queries : keys;
    const float* __restrict__ W    = (which == 0) ? Wq : (which == 1) ? Wk : Wv;
    const float* __restrict__ bias = (which == 0) ? bq : (which == 1) ? bk : bv;

    __shared__ float xs[8][H];
    *(float4*)(&xs[0][0] + t * 4) = *(const float4*)(x + (size_t)r0 * H + t * 4);
    __syncthreads();

    const int d  = t & (H - 1);
    const int rh = (t >> 7) * 4;            // local row base: 0 or 4
    float a0 = 0.f, a1 = 0.f, a2 = 0.f, a3 = 0.f;
    const float4* __restrict__ wrow4 = (const float4*)(W + (size_t)d * H);
    #pragma unroll 8
    for (int j4 = 0; j4 < H / 4; ++j4) {
        const float4 w = wrow4[j4];
        const int j = j4 * 4;
        a0 += xs[rh + 0][j] * w.x + xs[rh + 0][j + 1] * w.y
            + xs[rh + 0][j + 2] * w.z + xs[rh + 0][j + 3] * w.w;
        a1 += xs[rh + 1][j] * w.x + xs[rh + 1][j + 1] * w.y
            + xs[rh + 1][j + 2] * w.z + xs[rh + 1][j + 3] * w.w;
        a2 += xs[rh + 2][j] * w.x + xs[rh + 2][j + 1] * w.y
            + xs[rh + 2][j + 2] * w.z + xs[rh + 2][j + 3] * w.w;
        a3 += xs[rh + 3][j] * w.x + xs[rh + 3][j + 1] * w.y
            + xs[rh + 3][j + 2] * w.z + xs[rh + 3][j + 3] * w.w;
    }
    const float bb = bias[d];
    float o[4] = {a0 + bb, a1 + bb, a2 + bb, a3 + bb};

    if (which == 0) {
        #pragma unroll
        for (int rr = 0; rr < 4; ++rr)
            Qs[(size_t)(r0 + rh + rr) * H + d] = o[rr] * QSCALE;
    } else if (which == 1) {
        #pragma unroll
        for (int rr = 0; rr < 4; ++rr) {
            const size_t idx = (size_t)(r0 + rh + rr) * H + d;
            KpK[idx] = o[rr] + apK[idx];
        }
    } else {
        #pragma unroll
        for (int rr = 0; rr < 4; ++rr) {
            const size_t idx = (size_t)(r0 + rh + rr) * H + d;
            VpV[idx] = o[rr] + apV[idx];
        }
    }
}

// ---------------------------------------------------------------------------
// Explicit register double-buffer burst: 16 rows (2 per krow-lane) x 3 streams
// = 6 float4 loads per stage. Two stages in flight -> >=12 KB/wave outstanding.
// ---------------------------------------------------------------------------
struct Burst {
    float4 a0, a1, c0, c1, e0, e1;
};

__device__ __forceinline__ Burst load_burst(
    const float* __restrict__ s1, const float* __restrict__ s2,
    const float* __restrict__ s3, int k0, int krow, int c4)
{
    int r0 = k0 + krow;
    int r1 = k0 + krow + 8;
    r0 = r0 < L ? r0 : L - 1;   // clamp: harmless in-bounds read
    r1 = r1 < L ? r1 : L - 1;
    Burst bu;
    bu.a0 = *(const float4*)(s1 + (size_t)r0 * H + c4);
    bu.a1 = *(const float4*)(s1 + (size_t)r1 * H + c4);
    bu.c0 = *(const float4*)(s2 + (size_t)r0 * H + c4);
    bu.c1 = *(const float4*)(s2 + (size_t)r1 * H + c4);
    bu.e0 = *(const float4*)(s3 + (size_t)r0 * H + c4);
    bu.e1 = *(const float4*)(s3 + (size_t)r1 * H + c4);
    return bu;
}

// ---------------------------------------------------------------------------
// Kernel 2: fused attention. One block per (b,q). 256 threads:
//   thread t -> column c4=(t&31)*4 (float4), k-rows {k0+krow, k0+krow+8},
//   head h=(t&31)>>3. Register double-buffered streaming in both phases.
// ---------------------------------------------------------------------------
extern "C" __global__ __launch_bounds__(256, 2) void tama_attn(
    const float* __restrict__ Qs, const float* __restrict__ KpK,
    const float* __restrict__ VpV, const int* __restrict__ time_mask,
    const float* __restrict__ tK, const float* __restrict__ tV,
    const float* __restrict__ dK, const float* __restrict__ dV,
    float* __restrict__ out)
{
    const int bq = (int)gridDim.x - 1 - (int)blockIdx.x;  // heavy (high-q) first
    const int b = bq / L, q = bq - b * L;
    const int t = threadIdx.x;

    __shared__ float p[NH][LP];     // probs per head, zero-padded to LP
    __shared__ float red[8][H];     // output reduction scratch

    const int c4   = (t & 31) * 4;
    const int krow = t >> 5;        // 0..7
    const int h    = (t & 31) >> 3; // head 0..3
    const int sg   = t & 7;

    const bool tmq = time_mask[b * L + q] != 0;  // row-mask: whole q row NEG
    const int kA = tmq ? 0 : (q + 1);            // score phase extent
    const int kB = tmq ? L : (q + 1);            // output phase extent

    const float4 q4 = *(const float4*)(Qs + (size_t)bq * H + c4);
    const float* __restrict__ tKb = tK + (size_t)bq * L * H;
    const float* __restrict__ dKb = dK + (size_t)bq * L * H;
    const float* __restrict__ kpb = KpK + (size_t)b * L * H;

    // ---- Phase A: scores, 16 rows / stage, double-buffered ----
    if (kA > 0) {
        Burst cur = load_burst(tKb, dKb, kpb, 0, krow, c4);
        for (int k0 = 0; k0 < kA; k0 += 16) {
            Burst nxt;
            if (k0 + 16 < kA)  // wave-uniform branch
                nxt = load_burst(tKb, dKb, kpb, k0 + 16, krow, c4);
            const int ku0 = k0 + krow;
            const int ku1 = k0 + krow + 8;
            float s0 = q4.x * (cur.a0.x + cur.c0.x + cur.e0.x)
                     + q4.y * (cur.a0.y + cur.c0.y + cur.e0.y)
                     + q4.z * (cur.a0.z + cur.c0.z + cur.e0.z)
                     + q4.w * (cur.a0.w + cur.c0.w + cur.e0.w);
            float s1 = q4.x * (cur.a1.x + cur.c1.x + cur.e1.x)
                     + q4.y * (cur.a1.y + cur.c1.y + cur.e1.y)
                     + q4.z * (cur.a1.z + cur.c1.z + cur.e1.z)
                     + q4.w * (cur.a1.w + cur.c1.w + cur.e1.w);
            s0 += __shfl_xor(s0, 1); s0 += __shfl_xor(s0, 2); s0 += __shfl_xor(s0, 4);
            s1 += __shfl_xor(s1, 1); s1 += __shfl_xor(s1, 2); s1 += __shfl_xor(s1, 4);
            if (sg == 0 && ku0 <= q) p[h][ku0] = s0;
            if (sg == 0 && ku1 <= q) p[h][ku1] = s1;
            cur = nxt;
        }
    }
    __syncthreads();

    // ---- Softmax: wave w handles head w; lanes cover k = lane + 64*i ----
    {
        const int wv = t >> 6;
        const int lane = t & 63;
        float s0 = p[wv][lane];
        float s1 = p[wv][lane + 64];
        float s2 = p[wv][lane + 128];
        float s3 = (lane < L - 192) ? p[wv][lane + 192] : NEG;
        if (tmq || lane > q)       s0 = NEG;
        if (tmq || lane + 64 > q)  s1 = NEG;
        if (tmq || lane + 128 > q) s2 = NEG;
        if (tmq || lane + 192 > q) s3 = NEG;   // always true for lane >= 8
        float m = fmaxf(fmaxf(s0, s1), fmaxf(s2, s3));
        #pragma unroll
        for (int off = 32; off; off >>= 1) m = fmaxf(m, __shfl_xor(m, off));
        const float e0 = __expf(s0 - m);       // exp(NEG-m) underflows to 0.0f
        const float e1 = __expf(s1 - m);
        const float e2 = __expf(s2 - m);
        const float e3 = (lane < L - 192) ? __expf(s3 - m) : 0.f;
        float sum = e0 + e1 + e2 + e3;
        #pragma unroll
        for (int off = 32; off; off >>= 1) sum += __shfl_xor(sum, off);
        const float inv = 1.0f / sum;
        p[wv][lane]       = e0 * inv;
        p[wv][lane + 64]  = e1 * inv;
        p[wv][lane + 128] = e2 * inv;
        if (lane < L - 192) p[wv][lane + 192] = e3 * inv;
        if (lane < LP - L) p[wv][L + lane] = 0.f;   // zero pad 200..223
    }
    __syncthreads();

    // ---- Phase B: out[c] = sum_k p[h][k] * (VpV + tV + dV)[k][c] ----
    const float* __restrict__ tVb = tV + (size_t)bq * L * H;
    const float* __restrict__ dVb = dV + (size_t)bq * L * H;
    const float* __restrict__ vpb = VpV + (size_t)b * L * H;
    float ax = 0.f, ay = 0.f, az = 0.f, aw = 0.f;
    {
        Burst cur = load_burst(tVb, dVb, vpb, 0, krow, c4);
        for (int k0 = 0; k0 < kB; k0 += 16) {
            Burst nxt;
            if (k0 + 16 < kB)  // wave-uniform branch
                nxt = load_burst(tVb, dVb, vpb, k0 + 16, krow, c4);
            const float pk0 = p[h][k0 + krow];       // 0 beyond kB (exact)
            const float pk1 = p[h][k0 + krow + 8];
            ax += pk0 * (cur.a0.x + cur.c0.x + cur.e0.x)
                + pk1 * (cur.a1.x + cur.c1.x + cur.e1.x);
            ay += pk0 * (cur.a0.y + cur.c0.y + cur.e0.y)
                + pk1 * (cur.a1.y + cur.c1.y + cur.e1.y);
            az += pk0 * (cur.a0.z + cur.c0.z + cur.e0.z)
                + pk1 * (cur.a1.z + cur.c1.z + cur.e1.z);
            aw += pk0 * (cur.a0.w + cur.c0.w + cur.e0.w)
                + pk1 * (cur.a1.w + cur.c1.w + cur.e1.w);
            cur = nxt;
        }
    }
    red[krow][c4 + 0] = ax;
    red[krow][c4 + 1] = ay;
    red[krow][c4 + 2] = az;
    red[krow][c4 + 3] = aw;
    __syncthreads();
    if (t < 32) {
        float4 r = {0.f, 0.f, 0.f, 0.f};
        #pragma unroll
        for (int j = 0; j < 8; ++j) {
            r.x += red[j][t * 4 + 0];
            r.y += red[j][t * 4 + 1];
            r.z += red[j][t * 4 + 2];
            r.w += red[j][t * 4 + 3];
        }
        *(float4*)(out + (size_t)bq * H + t * 4) = r;
    }
}

// ---------------------------------------------------------------------------
extern "C" void kernel_launch(void* const* d_in, const int* in_sizes, int n_in,
                              void* d_out, int out_size, void* d_ws, size_t ws_size,
                              hipStream_t stream)
{
    const float* queries   = (const float*)d_in[0];
    const float* keys      = (const float*)d_in[1];
    const int*   time_mask = (const int*)d_in[2];
    // d_in[3] attn_mask unused: it is exactly triu(ones, k=1), i.e. (k > q)
    const float* tK  = (const float*)d_in[4];
    const float* tV  = (const float*)d_in[5];
    const float* dK  = (const float*)d_in[6];
    const float* dV  = (const float*)d_in[7];
    const float* apK = (const float*)d_in[8];
    const float* apV = (const float*)d_in[9];
    const float* Wq  = (const float*)d_in[10];
    const float* bqv = (const float*)d_in[11];
    const float* Wk  = (const float*)d_in[12];
    const float* bkv = (const float*)d_in[13];
    const float* Wv  = (const float*)d_in[14];
    const float* bvv = (const float*)d_in[15];

    float* Qs  = (float*)d_ws;                 // [B*L*H]
    float* KpK = Qs + (size_t)B * L * H;       // [B*L*H]
    float* VpV = KpK + (size_t)B * L * H;      // [B*L*H]  (total 2.46 MB)
    float* outp = (float*)d_out;

    hipLaunchKernelGGL(tama_proj, dim3(3 * (B * L) / 8), dim3(256), 0, stream,
                       queries, keys, apK, apV, Wq, bqv, Wk, bkv, Wv, bvv,
                       Qs, KpK, VpV);
    hipLaunchKernelGGL(tama_attn, dim3(B * L), dim3(256), 0, stream,
                       Qs, KpK, VpV, time_mask, tK, tV, dK, dV, outp);
}